// Round 3
// baseline (1042.466 us; speedup 1.0000x reference)
//
#include <hip/hip_runtime.h>
#include <hip/hip_bf16.h>

#define N_PTS 400000
#define KOFF 27
#define AP 72  // LDS W-row pitch in ushorts: 144B -> max 2-way bank alias (free)

typedef __attribute__((ext_vector_type(8))) short short8;
typedef __attribute__((ext_vector_type(4))) float float4v;

__device__ __forceinline__ unsigned short f2bf(float f) {
    union { float f; unsigned int u; } a; a.f = f;
    unsigned int u = a.u;
    unsigned int r = (u + 0x7FFFu + ((u >> 16) & 1u)) >> 16;
    return (unsigned short)r;
}

__device__ __forceinline__ float bf2f(unsigned short u) {
    union { unsigned int u; float f; } a; a.u = ((unsigned int)u) << 16;
    return a.f;
}

// ---- cast features fp32 -> bf16 ----
__global__ void cast_feat_kernel(const float* __restrict__ src,
                                 unsigned short* __restrict__ dst, int n4) {
    int i = blockIdx.x * blockDim.x + threadIdx.x;
    if (i >= n4) return;
    const float4* s4 = (const float4*)src;
    float4 v = s4[i];
    ushort4 o;
    o.x = f2bf(v.x); o.y = f2bf(v.y); o.z = f2bf(v.z); o.w = f2bf(v.w);
    ((ushort4*)dst)[i] = o;
}

// ---- one-shot prep: transpose+cast all 3 weight sets, zero all stats ----
__global__ void prep_w_all_kernel(const float* __restrict__ W1,
                                  const float* __restrict__ W2,
                                  const float* __restrict__ W3,
                                  unsigned short* __restrict__ Wt,
                                  float* __restrict__ stats) {
    int i = blockIdx.x * blockDim.x + threadIdx.x;
    if (i < 384) stats[i] = 0.0f;
    if (i >= KOFF * 64 * 64) return;
    int k = i >> 12;
    int co = (i >> 6) & 63;
    int ci = i & 63;
    int src = (k << 12) + (ci << 6) + co;
    const int WS = KOFF * 4096;
    Wt[i] = f2bf(W1[src]);
    Wt[i + WS] = f2bf(W2[src]);
    Wt[i + 2 * WS] = f2bf(W3[src]);
}

// ---- gather-GEMM + fused BN-stats ----
// A-fragments gathered DIRECTLY global -> registers (no LDS, no A-barrier).
// Each wave: 32 rows (2 M-tiles of 16). W double-buffered in LDS, prefetched
// one full k-iteration ahead through VGPRs; one barrier per k gates W only.
__global__ __launch_bounds__(256, 4)
void conv_kernel(const unsigned short* __restrict__ X,
                 const int* __restrict__ nbr,
                 const unsigned short* __restrict__ Wt,
                 float* __restrict__ Y,
                 float* __restrict__ stats) {
    __shared__ unsigned short lds_w[2][64 * AP];  // 2 x 9216 B
    const int tid = threadIdx.x;
    const int wave = tid >> 6;
    const int lane = tid & 63;
    const int quad = lane >> 4;
    const int l16 = lane & 15;
    const int p0 = blockIdx.x * 128;
    const char* Xb = (const char*)X;

    // nbr base offsets for this lane's two gather rows (mt=0,1)
    const long nb0 = (long)(p0 + wave * 32 + l16) * KOFF;
    const long nb1 = nb0 + 16 * KOFF;

    // W staging coords (256 threads x 2 chunks x 16B = 8KB)
    const int wrow = tid >> 3;
    const int wcol = (tid & 7) << 3;
    const int wrow2 = (tid + 256) >> 3;

    float4v acc[2][4];
    #pragma unroll
    for (int mt = 0; mt < 2; ++mt)
        #pragma unroll
        for (int t = 0; t < 4; ++t) acc[mt][t] = (float4v){0.f, 0.f, 0.f, 0.f};

    // ---- pipeline prologue (k=0 data, k=1 indices) ----
    int i0 = nbr[nb0] << 7;   // row byte offset (128B rows)
    int i1 = nbr[nb1] << 7;
    uint4 w0 = ((const uint4*)Wt)[tid];
    uint4 w1 = ((const uint4*)Wt)[tid + 256];
    short8 a00 = *(const short8*)(Xb + i0 + quad * 16);
    short8 a01 = *(const short8*)(Xb + i0 + quad * 16 + 64);
    short8 a10 = *(const short8*)(Xb + i1 + quad * 16);
    short8 a11 = *(const short8*)(Xb + i1 + quad * 16 + 64);
    *(uint4*)(&lds_w[0][wrow * AP + wcol]) = w0;
    *(uint4*)(&lds_w[0][wrow2 * AP + wcol]) = w1;
    int j0 = nbr[nb0 + 1] << 7;
    int j1 = nbr[nb1 + 1] << 7;
    __syncthreads();

    for (int k = 0; k < KOFF; ++k) {
        const int cb = k & 1;
        short8 n00, n01, n10, n11;
        uint4 v0, v1;
        if (k < KOFF - 1) {
            // issue W prefetch FIRST so its vmcnt wait doesn't drain the A gathers
            const uint4* Wk = (const uint4*)(Wt + (((size_t)(k + 1)) << 12));
            v0 = Wk[tid];
            v1 = Wk[tid + 256];
            n00 = *(const short8*)(Xb + j0 + quad * 16);
            n01 = *(const short8*)(Xb + j0 + quad * 16 + 64);
            n10 = *(const short8*)(Xb + j1 + quad * 16);
            n11 = *(const short8*)(Xb + j1 + quad * 16 + 64);
        }
        if (k < KOFF - 2) {
            j0 = nbr[nb0 + k + 2] << 7;
            j1 = nbr[nb1 + k + 2] << 7;
        }
        // B fragments from LDS, reused across both M-tiles
        #pragma unroll
        for (int t = 0; t < 4; ++t) {
            short8 b0 = *(const short8*)(&lds_w[cb][(t * 16 + l16) * AP + quad * 8]);
            short8 b1 = *(const short8*)(&lds_w[cb][(t * 16 + l16) * AP + 32 + quad * 8]);
            acc[0][t] = __builtin_amdgcn_mfma_f32_16x16x32_bf16(a00, b0, acc[0][t], 0, 0, 0);
            acc[0][t] = __builtin_amdgcn_mfma_f32_16x16x32_bf16(a01, b1, acc[0][t], 0, 0, 0);
            acc[1][t] = __builtin_amdgcn_mfma_f32_16x16x32_bf16(a10, b0, acc[1][t], 0, 0, 0);
            acc[1][t] = __builtin_amdgcn_mfma_f32_16x16x32_bf16(a11, b1, acc[1][t], 0, 0, 0);
        }
        if (k < KOFF - 1) {
            // stage W k+1 into the other buffer (waits only W's vmcnt slot)
            const int nbuf = cb ^ 1;
            *(uint4*)(&lds_w[nbuf][wrow * AP + wcol]) = v0;
            *(uint4*)(&lds_w[nbuf][wrow2 * AP + wcol]) = v1;
            a00 = n00; a01 = n01; a10 = n10; a11 = n11;
        }
        __syncthreads();
    }

    // ---- write Y: row = p0 + wave*32 + mt*16 + quad*4 + r, col = t*16 + l16 ----
    const int rb = p0 + wave * 32 + quad * 4;
    #pragma unroll
    for (int mt = 0; mt < 2; ++mt) {
        #pragma unroll
        for (int t = 0; t < 4; ++t) {
            #pragma unroll
            for (int r = 0; r < 4; ++r) {
                Y[(size_t)(rb + mt * 16 + r) * 64 + t * 16 + l16] = acc[mt][t][r];
            }
        }
    }

    // ---- fused BN stats: shuffle across quads -> LDS -> 1 atomic pass/block ----
    float* red = (float*)lds_w;
    if (tid < 128) red[tid] = 0.0f;
    __syncthreads();
    #pragma unroll
    for (int t = 0; t < 4; ++t) {
        float s = 0.f, ss = 0.f;
        #pragma unroll
        for (int mt = 0; mt < 2; ++mt) {
            #pragma unroll
            for (int r = 0; r < 4; ++r) {
                float v = acc[mt][t][r];
                s += v;
                ss += v * v;
            }
        }
        s += __shfl_down(s, 32);
        s += __shfl_down(s, 16);
        ss += __shfl_down(ss, 32);
        ss += __shfl_down(ss, 16);
        if (lane < 16) {
            atomicAdd(&red[t * 16 + l16], s);
            atomicAdd(&red[64 + t * 16 + l16], ss);
        }
    }
    __syncthreads();
    if (tid < 128) atomicAdd(&stats[tid], red[tid]);
}

// ---- bn + leakyrelu -> bf16 output (input to next conv) ----
__global__ void bnact_kernel(const float* __restrict__ Y, const float* __restrict__ stats,
                             const float* __restrict__ g, const float* __restrict__ b,
                             unsigned short* __restrict__ Xb, float slope) {
    __shared__ float scale[64], shift[64];
    int tid = threadIdx.x;
    if (tid < 64) {
        float m = stats[tid] * (1.0f / N_PTS);
        float v = stats[64 + tid] * (1.0f / N_PTS) - m * m;
        float rs = rsqrtf(v + 1e-4f);
        float sc = rs * g[tid];
        scale[tid] = sc;
        shift[tid] = b[tid] - m * sc;
    }
    __syncthreads();
    int i = blockIdx.x * blockDim.x + tid;
    const int total = N_PTS * 16;
    if (i >= total) return;
    int cb = (i & 15) << 2;
    float4 y = ((const float4*)Y)[i];
    float o0 = y.x * scale[cb] + shift[cb];
    float o1 = y.y * scale[cb + 1] + shift[cb + 1];
    float o2 = y.z * scale[cb + 2] + shift[cb + 2];
    float o3 = y.w * scale[cb + 3] + shift[cb + 3];
    o0 = o0 >= 0.f ? o0 : slope * o0;
    o1 = o1 >= 0.f ? o1 : slope * o1;
    o2 = o2 >= 0.f ? o2 : slope * o2;
    o3 = o3 >= 0.f ? o3 : slope * o3;
    ushort4 o;
    o.x = f2bf(o0); o.y = f2bf(o1); o.z = f2bf(o2); o.w = f2bf(o3);
    ((ushort4*)Xb)[i] = o;
}

// ---- final: bn3 + residual + leakyrelu(0.333) -> fp32 d_out (in place over Y) ----
__global__ void bnact_final_kernel(float* __restrict__ Y, const float* __restrict__ stats,
                                   const float* __restrict__ g, const float* __restrict__ b,
                                   const unsigned short* __restrict__ res) {
    __shared__ float scale[64], shift[64];
    int tid = threadIdx.x;
    if (tid < 64) {
        float m = stats[tid] * (1.0f / N_PTS);
        float v = stats[64 + tid] * (1.0f / N_PTS) - m * m;
        float rs = rsqrtf(v + 1e-4f);
        float sc = rs * g[tid];
        scale[tid] = sc;
        shift[tid] = b[tid] - m * sc;
    }
    __syncthreads();
    int i = blockIdx.x * blockDim.x + tid;
    const int total = N_PTS * 16;
    if (i >= total) return;
    int cb = (i & 15) << 2;
    float4 y = ((const float4*)Y)[i];
    ushort4 r4 = ((const ushort4*)res)[i];
    float o0 = y.x * scale[cb] + shift[cb] + bf2f(r4.x);
    float o1 = y.y * scale[cb + 1] + shift[cb + 1] + bf2f(r4.y);
    float o2 = y.z * scale[cb + 2] + shift[cb + 2] + bf2f(r4.z);
    float o3 = y.w * scale[cb + 3] + shift[cb + 3] + bf2f(r4.w);
    o0 = o0 >= 0.f ? o0 : 0.333f * o0;
    o1 = o1 >= 0.f ? o1 : 0.333f * o1;
    o2 = o2 >= 0.f ? o2 : 0.333f * o2;
    o3 = o3 >= 0.f ? o3 : 0.333f * o3;
    float4 o; o.x = o0; o.y = o1; o.z = o2; o.w = o3;
    ((float4*)Y)[i] = o;
}

extern "C" void kernel_launch(void* const* d_in, const int* in_sizes, int n_in,
                              void* d_out, int out_size, void* d_ws, size_t ws_size,
                              hipStream_t stream) {
    const float* feat = (const float*)d_in[0];
    const int* nbr = (const int*)d_in[1];
    const float* W1 = (const float*)d_in[2];
    const float* g1 = (const float*)d_in[3];
    const float* b1 = (const float*)d_in[4];
    const float* W2 = (const float*)d_in[5];
    const float* g2 = (const float*)d_in[6];
    const float* b2 = (const float*)d_in[7];
    const float* W3 = (const float*)d_in[8];
    const float* g3 = (const float*)d_in[9];
    const float* b3 = (const float*)d_in[10];
    float* Y = (float*)d_out;

    char* ws = (char*)d_ws;
    const size_t BF_BYTES = (size_t)N_PTS * 64 * 2;  // 51.2 MB
    unsigned short* B0 = (unsigned short*)ws;
    unsigned short* B1 = (unsigned short*)(ws + BF_BYTES);
    unsigned short* Wt = (unsigned short*)(ws + 2 * BF_BYTES);
    float* stats = (float*)(ws + 2 * BF_BYTES + (size_t)3 * KOFF * 4096 * 2);

    const int WSTRIDE = KOFF * 4096;  // 110592

    cast_feat_kernel<<<25000, 256, 0, stream>>>(feat, B0, N_PTS * 16);
    prep_w_all_kernel<<<(KOFF * 4096 + 255) / 256, 256, 0, stream>>>(W1, W2, W3, Wt, stats);

    // block 1
    conv_kernel<<<N_PTS / 128, 256, 0, stream>>>(B0, nbr, Wt, Y, stats);
    bnact_kernel<<<25000, 256, 0, stream>>>(Y, stats, g1, b1, B1, 0.05f);
    // block 2
    conv_kernel<<<N_PTS / 128, 256, 0, stream>>>(B1, nbr, Wt + WSTRIDE, Y, stats + 128);
    bnact_kernel<<<25000, 256, 0, stream>>>(Y, stats + 128, g2, b2, B0, 0.05f);
    // block 3 + residual
    conv_kernel<<<N_PTS / 128, 256, 0, stream>>>(B0, nbr, Wt + 2 * WSTRIDE, Y, stats + 256);
    bnact_final_kernel<<<25000, 256, 0, stream>>>(Y, stats + 256, g3, b3, B1);
}